// Round 1
// baseline (257.749 us; speedup 1.0000x reference)
//
#include <hip/hip_runtime.h>
#include <math.h>

// out[h][i][j] = |j - i| * m, m = alpha[h] if (i==0 || j==0)
//                               else gamma[h] if j > i
//                               else beta[h]  if j < i   (i==j -> dist=0, don't care)
// One block per (h, i) row; float4 stores across j.

__global__ __launch_bounds__(256) void bidirectional_alibi_kernel(
    const float* __restrict__ alpha,
    const float* __restrict__ beta,
    const float* __restrict__ gamma,
    float* __restrict__ out,
    int S)
{
    const int bid = blockIdx.x;       // bid = h * S + i
    const int i   = bid % S;
    const int h   = bid / S;

    const float a = alpha[h];
    const float b = beta[h];
    const float g = gamma[h];

    const float fi = (float)i;
    // For i != 0: sel(j) = a if j==0 else (g if j>i else b)
    // For i == 0: sel(j) = a for all j
    const bool  row0 = (i == 0);

    float* row = out + (size_t)bid * (size_t)S;
    const int n4 = S >> 2;

    for (int t = threadIdx.x; t < n4; t += blockDim.x) {
        const int j0 = t << 2;
        float4 v;
        float* vp = (float*)&v;
        #pragma unroll
        for (int k = 0; k < 4; ++k) {
            const int   j    = j0 + k;
            const float fj   = (float)j;
            const float dist = fabsf(fj - fi);
            float sel = (j > i) ? g : b;
            if (row0 || j == 0) sel = a;
            vp[k] = dist * sel;
        }
        ((float4*)row)[t] = v;
    }

    // Scalar tail if S % 4 != 0 (not hit for S=2048, kept for generality)
    const int tail_start = n4 << 2;
    for (int j = tail_start + (int)threadIdx.x; j < S; j += blockDim.x) {
        const float dist = fabsf((float)j - fi);
        float sel = (j > i) ? g : b;
        if (row0 || j == 0) sel = a;
        row[j] = dist * sel;
    }
}

extern "C" void kernel_launch(void* const* d_in, const int* in_sizes, int n_in,
                              void* d_out, int out_size, void* d_ws, size_t ws_size,
                              hipStream_t stream) {
    const float* alpha = (const float*)d_in[0];
    const float* beta  = (const float*)d_in[1];
    const float* gamma = (const float*)d_in[2];
    float* out = (float*)d_out;

    const int H = in_sizes[0];                       // 16
    const long long ss = (long long)out_size / H;    // S*S
    const int S = (int)(sqrt((double)ss) + 0.5);     // 2048

    const int blocks = H * S;                        // one block per (h, i) row
    bidirectional_alibi_kernel<<<blocks, 256, 0, stream>>>(alpha, beta, gamma, out, S);
}